// Round 2
// baseline (1272.910 us; speedup 1.0000x reference)
//
#include <hip/hip_runtime.h>
#include <hip/hip_bf16.h>
#include <math.h>

typedef unsigned short u16;
typedef __attribute__((ext_vector_type(8))) short v8s;
typedef __attribute__((ext_vector_type(4))) float v4f;

__device__ __forceinline__ float bf2f(u16 u){
  union { float f; unsigned int i; } v; v.i = ((unsigned int)u) << 16; return v.f;
}
__device__ __forceinline__ u16 f2bf(float f){
  union { __hip_bfloat16 h; u16 u; } cv; cv.h = __float2bfloat16(f); return cv.u;
}
// dtype detect: p points at a tensor of ones. bf16 -> u16[0]=0x3F80, f32 -> u16[0]=0x0000
__device__ __forceinline__ bool det_bf16(const void* p){
  return ((const u16*)p)[0] != 0;
}
__device__ __forceinline__ float ldp(const void* p, size_t i, bool bf){
  return bf ? bf2f(((const u16*)p)[i]) : ((const float*)p)[i];
}
__device__ __forceinline__ void ld8f(const void* p, size_t i, bool bf, float* o){
  if (bf){
    v8s a = *(const v8s*)((const u16*)p + i);
    #pragma unroll
    for (int j=0;j<8;j++) o[j]=bf2f((u16)a[j]);
  } else {
    const float4* q=(const float4*)((const float*)p + i);
    float4 a=q[0], b=q[1];
    o[0]=a.x;o[1]=a.y;o[2]=a.z;o[3]=a.w;o[4]=b.x;o[5]=b.y;o[6]=b.z;o[7]=b.w;
  }
}

#define MFMA(a,b,c) __builtin_amdgcn_mfma_f32_16x16x32_bf16((a),(b),(c),0,0,0)

// ---- repack: W[K,N] (f32 or bf16) row-major -> canonical bf16 B-fragment-major ----
// dst[((kb*(N/16)+nb)*64+lane)*8+j] = W[kb*32+(lane>>4)*8+j][nb*16+(lane&15)]
__global__ __launch_bounds__(64) void repack_kernel(
    const void* __restrict__ symW, const void* __restrict__ Wqkv,
    const void* __restrict__ Wo, const void* __restrict__ W1, const void* __restrict__ W2,
    u16* __restrict__ wf_sym, u16* __restrict__ wf_qkv, u16* __restrict__ wf_o,
    u16* __restrict__ wf_1, u16* __restrict__ wf_2, const void* __restrict__ dtp)
{
  bool bf = det_bf16(dtp);
  int idx = blockIdx.x;
  const void* src; u16* dst; int N, kb, nb; size_t soff;
  if (idx < 32) { src = symW; dst = wf_sym; N = 256; kb = idx >> 4; nb = idx & 15; soff = 0; }
  else {
    idx -= 32;
    int lay = idx / 768, r = idx % 768;
    if (r < 384) { N = 768; src = Wqkv; soff = (size_t)lay*196608; dst = wf_qkv + lay*196608; kb = r/48; nb = r%48; }
    else {
      r -= 384; int which = r >> 7, rr = r & 127; N = 256; kb = rr >> 4; nb = rr & 15;
      soff = (size_t)lay*65536;
      if (which == 0)      { src = Wo; dst = wf_o + lay*65536; }
      else if (which == 1) { src = W1; dst = wf_1 + lay*65536; }
      else                 { src = W2; dst = wf_2 + lay*65536; }
    }
  }
  int ln = threadIdx.x;
  int n  = nb*16 + (ln & 15);
  int k0 = kb*32 + (ln >> 4)*8;
  u16* d = dst + (((size_t)(kb*(N>>4) + nb))*64 + ln)*8;
  #pragma unroll
  for (int j = 0; j < 8; j++) d[j] = f2bf(ldp(src, soff + (size_t)(k0+j)*N + n, bf));
}

// ---- prep: sym_proj = LN(sym_feat @ sym_W + b), assemble x0 = stack + tte ----
__global__ __launch_bounds__(256) void prep_kernel(
    const void* __restrict__ gemb, const void* __restrict__ pemb,
    const void* __restrict__ symf, const void* __restrict__ ppi,
    const u16* __restrict__ wf_sym, const void* __restrict__ symb,
    const void* __restrict__ slng, const void* __restrict__ slnb,
    const void* __restrict__ tte, u16* __restrict__ x)
{
  __shared__ __align__(16) u16 sf[64*88];     // stride 88 elems = 176B (16B-mult)
  __shared__ __align__(16) u16 sout[64*264];
  __shared__ float2 red[64*4];
  __shared__ float2 stats[64];
  bool bf = det_bf16(slng);
  int t = threadIdx.x;
  int s0 = blockIdx.x * 64;
  { // stage sym_feat tile [64][64] -> bf16 LDS
    int r = t >> 2, p = t & 3;
    float tmp[16];
    ld8f(symf, (size_t)(s0 + r)*64 + p*16,     bf, tmp);
    ld8f(symf, (size_t)(s0 + r)*64 + p*16 + 8, bf, tmp+8);
    u16* d = sf + r*88 + p*16;
    #pragma unroll
    for (int j=0;j<16;j++) d[j]=f2bf(tmp[j]);
  }
  __syncthreads();
  int w = t >> 6, ln = t & 63;
  { // GEMM [64,64]@[64,256]
    v4f acc[4][4];
    v4f z = {0.f,0.f,0.f,0.f};
    #pragma unroll
    for (int mb=0; mb<4; mb++) for (int nbi=0; nbi<4; nbi++) acc[mb][nbi] = z;
    #pragma unroll
    for (int kb=0; kb<2; kb++){
      v8s a[4];
      #pragma unroll
      for (int mb=0; mb<4; mb++)
        a[mb] = *(const v8s*)(sf + (mb*16+(ln&15))*88 + kb*32 + (ln>>4)*8);
      #pragma unroll
      for (int nbi=0; nbi<4; nbi++){
        int nb = w*4 + nbi;
        v8s bfr = *(const v8s*)(wf_sym + ((kb*16+nb)*64 + ln)*8);
        #pragma unroll
        for (int mb=0; mb<4; mb++) acc[mb][nbi] = MFMA(a[mb], bfr, acc[mb][nbi]);
      }
    }
    #pragma unroll
    for (int nbi=0; nbi<4; nbi++){
      int col = (w*4+nbi)*16 + (ln&15);
      float bias = ldp(symb, col, bf);
      #pragma unroll
      for (int mb=0; mb<4; mb++){
        int row = mb*16 + (ln>>4)*4;
        #pragma unroll
        for (int i=0;i<4;i++) sout[(row+i)*264 + col] = f2bf(acc[mb][nbi][i] + bias);
      }
    }
  }
  __syncthreads();
  int r = t >> 2, p = t & 3;
  float vv[64];
  {
    float s=0.f, sq=0.f;
    for (int i=0;i<64;i++){ float v = bf2f(sout[r*264 + p*64 + i]); vv[i]=v; s+=v; sq+=v*v; }
    red[r*4+p] = make_float2(s, sq);
  }
  __syncthreads();
  if (t < 64){
    float s=0.f, sq=0.f;
    for (int q=0;q<4;q++){ float2 e = red[t*4+q]; s+=e.x; sq+=e.y; }
    float m = s*(1.f/256.f), var = sq*(1.f/256.f) - m*m;
    stats[t] = make_float2(m, rsqrtf(var + 1e-5f));
  }
  __syncthreads();
  {
    float2 st = stats[r];
    int sg = s0 + r;
    u16* dst = x + ((size_t)sg*4 + 2)*256 + p*64;
    for (int i=0;i<64;i++){
      int col = p*64 + i;
      float o = (vv[i]-st.x)*st.y*ldp(slng,col,bf) + ldp(slnb,col,bf) + ldp(tte,2*256+col,bf);
      dst[i] = f2bf(o);
    }
  }
  { // tokens 0,1,3: emb + tte
    int sg = s0 + r;
    const void* srcs[3] = {gemb, pemb, ppi};
    const int  toks[3] = {0, 1, 3};
    for (int z=0; z<3; z++){
      u16* dst = x + ((size_t)sg*4 + toks[z])*256 + p*64;
      for (int i=0;i<64;i+=8){
        float a8[8];
        ld8f(srcs[z], (size_t)sg*256 + p*64 + i, bf, a8);
        v8s o;
        #pragma unroll
        for (int j=0;j<8;j++){
          int col = p*64 + i + j;
          o[j] = (short)f2bf(a8[j] + ldp(tte, toks[z]*256 + col, bf));
        }
        *(v8s*)(dst + i) = o;
      }
    }
  }
}

// ---- attention layer: LN1 -> qkv -> attn(4x4/head) -> o@Wo + residual ----
__global__ __launch_bounds__(256) void attn_kernel(
    u16* __restrict__ x, const u16* __restrict__ wf_qkv, const void* __restrict__ bqkv,
    const u16* __restrict__ wf_o, const void* __restrict__ bo,
    const void* __restrict__ ln1g, const void* __restrict__ ln1b,
    const void* __restrict__ dtp, int lay)
{
  __shared__ __align__(16) u16 hl[32*264];     // h, later reused for o
  __shared__ __align__(16) u16 qkvl[32*776];
  __shared__ float2 red[32*8];
  __shared__ float2 stats[32];
  bool bf = det_bf16(dtp);
  int t = threadIdx.x;
  int row0 = blockIdx.x * 32;
  // phase 1: LN1
  float xv[32];
  {
    int r = t>>3, p = t&7;
    const u16* src = x + (size_t)(row0 + r)*256 + p*32;
    float s=0.f, sq=0.f;
    #pragma unroll
    for (int c8=0;c8<4;c8++){
      v8s a = *(const v8s*)(src + c8*8);
      #pragma unroll
      for (int j=0;j<8;j++){ float v = bf2f((u16)a[j]); xv[c8*8+j]=v; s+=v; sq+=v*v; }
    }
    red[r*8+p] = make_float2(s,sq);
  }
  __syncthreads();
  if (t<32){
    float s=0.f, sq=0.f;
    for (int p=0;p<8;p++){ float2 e=red[t*8+p]; s+=e.x; sq+=e.y; }
    float m=s*(1.f/256.f), var=sq*(1.f/256.f)-m*m;
    stats[t]=make_float2(m, rsqrtf(var+1e-5f));
  }
  __syncthreads();
  {
    int r=t>>3, p=t&7;
    float2 st=stats[r];
    for (int i=0;i<32;i++){
      int col=p*32+i;
      hl[r*264+col] = f2bf((xv[i]-st.x)*st.y*ldp(ln1g,(size_t)lay*256+col,bf) + ldp(ln1b,(size_t)lay*256+col,bf));
    }
  }
  __syncthreads();
  int w=t>>6, ln=t&63;
  // phase 2: qkv = h @ Wqkv + bqkv  [32,256]@[256,768]
  {
    const u16* wq = wf_qkv + (size_t)lay*196608;
    v4f acc[2][12];
    v4f z={0.f,0.f,0.f,0.f};
    #pragma unroll
    for (int mb=0;mb<2;mb++) for (int nbi=0;nbi<12;nbi++) acc[mb][nbi]=z;
    for (int kb=0;kb<8;kb++){
      v8s a0 = *(const v8s*)(hl + ((ln&15))*264 + kb*32 + (ln>>4)*8);
      v8s a1 = *(const v8s*)(hl + (16+(ln&15))*264 + kb*32 + (ln>>4)*8);
      #pragma unroll
      for (int nbi=0;nbi<12;nbi++){
        int nb = w*12+nbi;
        v8s bfr = *(const v8s*)(wq + (((size_t)kb*48+nb)*64+ln)*8);
        acc[0][nbi]=MFMA(a0,bfr,acc[0][nbi]);
        acc[1][nbi]=MFMA(a1,bfr,acc[1][nbi]);
      }
    }
    #pragma unroll
    for (int nbi=0;nbi<12;nbi++){
      int col=(w*12+nbi)*16+(ln&15);
      float bias = ldp(bqkv, (size_t)lay*768+col, bf);
      #pragma unroll
      for (int mb=0;mb<2;mb++){
        int row=mb*16+(ln>>4)*4;
        #pragma unroll
        for (int i=0;i<4;i++) qkvl[(row+i)*776+col]=f2bf(acc[mb][nbi][i]+bias);
      }
    }
  }
  __syncthreads();
  // phase 3: per-(sample,head,qrow) attention over 4 keys
  {
    int s=t>>5, hd=(t>>2)&7, qi=t&3;
    int qrow=s*4+qi;
    float q[32];
    const u16* qp = qkvl + qrow*776 + hd*32;
    #pragma unroll
    for (int c8=0;c8<4;c8++){ v8s a=*(const v8s*)(qp+c8*8);
      #pragma unroll
      for (int j=0;j<8;j++) q[c8*8+j]=bf2f((u16)a[j]); }
    float sc[4];
    #pragma unroll
    for (int j4=0;j4<4;j4++){
      const u16* kp = qkvl + (s*4+j4)*776 + 256 + hd*32;
      float d=0.f;
      #pragma unroll
      for (int c8=0;c8<4;c8++){ v8s a=*(const v8s*)(kp+c8*8);
        #pragma unroll
        for (int j=0;j<8;j++) d += q[c8*8+j]*bf2f((u16)a[j]); }
      sc[j4]=d*0.17677669529663687f;
    }
    float mx = fmaxf(fmaxf(sc[0],sc[1]),fmaxf(sc[2],sc[3]));
    float ps=0.f;
    #pragma unroll
    for (int j4=0;j4<4;j4++){ sc[j4]=__expf(sc[j4]-mx); ps+=sc[j4]; }
    float inv=1.f/ps;
    float o[32];
    #pragma unroll
    for (int c=0;c<32;c++) o[c]=0.f;
    #pragma unroll
    for (int j4=0;j4<4;j4++){
      float pw = sc[j4]*inv;
      const u16* vp = qkvl + (s*4+j4)*776 + 512 + hd*32;
      #pragma unroll
      for (int c8=0;c8<4;c8++){ v8s a=*(const v8s*)(vp+c8*8);
        #pragma unroll
        for (int j=0;j<8;j++) o[c8*8+j] += pw*bf2f((u16)a[j]); }
    }
    u16* op = hl + qrow*264 + hd*32;
    #pragma unroll
    for (int c=0;c<32;c++) op[c]=f2bf(o[c]);
  }
  __syncthreads();
  // phase 4: x += o @ Wo + bo
  {
    const u16* wo = wf_o + (size_t)lay*65536;
    v4f acc[2][4];
    v4f z={0.f,0.f,0.f,0.f};
    #pragma unroll
    for (int mb=0;mb<2;mb++) for (int nbi=0;nbi<4;nbi++) acc[mb][nbi]=z;
    for (int kb=0;kb<8;kb++){
      v8s a0 = *(const v8s*)(hl + ((ln&15))*264 + kb*32 + (ln>>4)*8);
      v8s a1 = *(const v8s*)(hl + (16+(ln&15))*264 + kb*32 + (ln>>4)*8);
      #pragma unroll
      for (int nbi=0;nbi<4;nbi++){
        int nb=w*4+nbi;
        v8s bfr=*(const v8s*)(wo+(((size_t)kb*16+nb)*64+ln)*8);
        acc[0][nbi]=MFMA(a0,bfr,acc[0][nbi]);
        acc[1][nbi]=MFMA(a1,bfr,acc[1][nbi]);
      }
    }
    #pragma unroll
    for (int nbi=0;nbi<4;nbi++){
      int col=(w*4+nbi)*16+(ln&15);
      float bias=ldp(bo,(size_t)lay*256+col,bf);
      #pragma unroll
      for (int mb=0;mb<2;mb++){
        int row=mb*16+(ln>>4)*4;
        #pragma unroll
        for (int i=0;i<4;i++){
          size_t gi=(size_t)(row0+row+i)*256+col;
          x[gi]=f2bf(bf2f(x[gi])+acc[mb][nbi][i]+bias);
        }
      }
    }
  }
}

// ---- FFN layer: LN2 -> gelu(h@W1+b1)@W2 + b2 + residual ----
__global__ __launch_bounds__(256) void ffn_kernel(
    u16* __restrict__ x, const u16* __restrict__ wf_1, const void* __restrict__ b1p,
    const u16* __restrict__ wf_2, const void* __restrict__ b2p,
    const void* __restrict__ ln2g, const void* __restrict__ ln2b,
    const void* __restrict__ dtp, int lay)
{
  __shared__ __align__(16) u16 hl[64*264];
  __shared__ __align__(16) u16 tl[64*264];
  __shared__ float2 red[64*4];
  __shared__ float2 stats[64];
  bool bf = det_bf16(dtp);
  int t=threadIdx.x;
  int row0=blockIdx.x*64;
  float xv[64];
  {
    int r=t>>2, p=t&3;
    const u16* src = x + (size_t)(row0+r)*256 + p*64;
    float s=0.f, sq=0.f;
    #pragma unroll
    for (int c8=0;c8<8;c8++){
      v8s a=*(const v8s*)(src+c8*8);
      #pragma unroll
      for (int j=0;j<8;j++){ float v=bf2f((u16)a[j]); xv[c8*8+j]=v; s+=v; sq+=v*v; }
    }
    red[r*4+p]=make_float2(s,sq);
  }
  __syncthreads();
  if (t<64){
    float s=0.f, sq=0.f;
    for (int q=0;q<4;q++){ float2 e=red[t*4+q]; s+=e.x; sq+=e.y; }
    float m=s*(1.f/256.f), var=sq*(1.f/256.f)-m*m;
    stats[t]=make_float2(m, rsqrtf(var+1e-5f));
  }
  __syncthreads();
  {
    int r=t>>2, p=t&3;
    float2 st=stats[r];
    for (int i=0;i<64;i++){
      int col=p*64+i;
      hl[r*264+col]=f2bf((xv[i]-st.x)*st.y*ldp(ln2g,(size_t)lay*256+col,bf)+ldp(ln2b,(size_t)lay*256+col,bf));
    }
  }
  __syncthreads();
  int w=t>>6, ln=t&63;
  { // GEMM1 + gelu
    const u16* w1=wf_1+(size_t)lay*65536;
    v4f acc[4][4];
    v4f z={0.f,0.f,0.f,0.f};
    #pragma unroll
    for (int mb=0;mb<4;mb++) for (int nbi=0;nbi<4;nbi++) acc[mb][nbi]=z;
    for (int kb=0;kb<8;kb++){
      v8s a[4];
      #pragma unroll
      for (int mb=0;mb<4;mb++)
        a[mb]=*(const v8s*)(hl+(mb*16+(ln&15))*264+kb*32+(ln>>4)*8);
      #pragma unroll
      for (int nbi=0;nbi<4;nbi++){
        int nb=w*4+nbi;
        v8s bfr=*(const v8s*)(w1+(((size_t)kb*16+nb)*64+ln)*8);
        #pragma unroll
        for (int mb=0;mb<4;mb++) acc[mb][nbi]=MFMA(a[mb],bfr,acc[mb][nbi]);
      }
    }
    #pragma unroll
    for (int nbi=0;nbi<4;nbi++){
      int col=(w*4+nbi)*16+(ln&15);
      float bias=ldp(b1p,(size_t)lay*256+col,bf);
      #pragma unroll
      for (int mb=0;mb<4;mb++){
        int row=mb*16+(ln>>4)*4;
        #pragma unroll
        for (int i=0;i<4;i++){
          float u=acc[mb][nbi][i]+bias;
          float g=0.5f*u*(1.f+erff(u*0.70710678118f));
          tl[(row+i)*264+col]=f2bf(g);
        }
      }
    }
  }
  __syncthreads();
  { // GEMM2 + residual
    const u16* w2=wf_2+(size_t)lay*65536;
    v4f acc[4][4];
    v4f z={0.f,0.f,0.f,0.f};
    #pragma unroll
    for (int mb=0;mb<4;mb++) for (int nbi=0;nbi<4;nbi++) acc[mb][nbi]=z;
    for (int kb=0;kb<8;kb++){
      v8s a[4];
      #pragma unroll
      for (int mb=0;mb<4;mb++)
        a[mb]=*(const v8s*)(tl+(mb*16+(ln&15))*264+kb*32+(ln>>4)*8);
      #pragma unroll
      for (int nbi=0;nbi<4;nbi++){
        int nb=w*4+nbi;
        v8s bfr=*(const v8s*)(w2+(((size_t)kb*16+nb)*64+ln)*8);
        #pragma unroll
        for (int mb=0;mb<4;mb++) acc[mb][nbi]=MFMA(a[mb],bfr,acc[mb][nbi]);
      }
    }
    #pragma unroll
    for (int nbi=0;nbi<4;nbi++){
      int col=(w*4+nbi)*16+(ln&15);
      float bias=ldp(b2p,(size_t)lay*256+col,bf);
      #pragma unroll
      for (int mb=0;mb<4;mb++){
        int row=mb*16+(ln>>4)*4;
        #pragma unroll
        for (int i=0;i<4;i++){
          size_t gi=(size_t)(row0+row+i)*256+col;
          x[gi]=f2bf(bf2f(x[gi])+acc[mb][nbi][i]+bias);
        }
      }
    }
  }
}

// ---- final: LN(final) per token -> mean over 4 -> LN(out) ----
__global__ __launch_bounds__(256) void final_kernel(
    const u16* __restrict__ x, const void* __restrict__ flng, const void* __restrict__ flnb,
    const void* __restrict__ olng, const void* __restrict__ olnb, void* __restrict__ out)
{
  __shared__ float2 red[16*4*16];
  __shared__ float2 rstats[16*4];
  __shared__ float2 red2[16*16];
  __shared__ float2 ostats[16];
  bool bf = det_bf16(flng);   // final_ln_g is ones
  int t=threadIdx.x;
  int s=t>>4, p=t&15;
  int sg=blockIdx.x*16+s;
  float xv[4][16];
  #pragma unroll
  for (int r=0;r<4;r++){
    const u16* src=x+((size_t)sg*4+r)*256+p*16;
    v8s a=*(const v8s*)src, b=*(const v8s*)(src+8);
    float ssum=0.f, ssq=0.f;
    #pragma unroll
    for (int j=0;j<8;j++){ float v=bf2f((u16)a[j]); xv[r][j]=v; ssum+=v; ssq+=v*v; }
    #pragma unroll
    for (int j=0;j<8;j++){ float v=bf2f((u16)b[j]); xv[r][8+j]=v; ssum+=v; ssq+=v*v; }
    red[(s*4+r)*16+p]=make_float2(ssum,ssq);
  }
  __syncthreads();
  if (t<64){
    int ss=t>>2, rr=t&3;
    float s1=0.f, s2=0.f;
    for (int q=0;q<16;q++){ float2 e=red[(ss*4+rr)*16+q]; s1+=e.x; s2+=e.y; }
    float m=s1*(1.f/256.f), var=s2*(1.f/256.f)-m*m;
    rstats[ss*4+rr]=make_float2(m, rsqrtf(var+1e-5f));
  }
  __syncthreads();
  float y[16];
  {
    float ssum=0.f, ssq=0.f;
    float2 st0=rstats[s*4+0], st1=rstats[s*4+1], st2=rstats[s*4+2], st3=rstats[s*4+3];
    #pragma unroll
    for (int j=0;j<16;j++){
      int col=p*16+j;
      float g=ldp(flng,col,bf), bb=ldp(flnb,col,bf);
      float acc=(xv[0][j]-st0.x)*st0.y*g+bb;
      acc+=(xv[1][j]-st1.x)*st1.y*g+bb;
      acc+=(xv[2][j]-st2.x)*st2.y*g+bb;
      acc+=(xv[3][j]-st3.x)*st3.y*g+bb;
      float v=acc*0.25f;
      y[j]=v; ssum+=v; ssq+=v*v;
    }
    red2[s*16+p]=make_float2(ssum,ssq);
  }
  __syncthreads();
  if (t<16){
    float s1=0.f, s2=0.f;
    for (int q=0;q<16;q++){ float2 e=red2[t*16+q]; s1+=e.x; s2+=e.y; }
    float m=s1*(1.f/256.f), var=s2*(1.f/256.f)-m*m;
    ostats[t]=make_float2(m, rsqrtf(var+1e-5f));
  }
  __syncthreads();
  {
    float2 st=ostats[s];
    if (bf){
      u16* dst=(u16*)out+(size_t)sg*256+p*16;
      #pragma unroll
      for (int j=0;j<16;j++){
        int col=p*16+j;
        dst[j]=f2bf((y[j]-st.x)*st.y*ldp(olng,col,bf)+ldp(olnb,col,bf));
      }
    } else {
      float* dst=(float*)out+(size_t)sg*256+p*16;
      #pragma unroll
      for (int j=0;j<16;j++){
        int col=p*16+j;
        dst[j]=(y[j]-st.x)*st.y*ldp(olng,col,bf)+ldp(olnb,col,bf);
      }
    }
  }
}

extern "C" void kernel_launch(void* const* d_in, const int* in_sizes, int n_in,
                              void* d_out, int out_size, void* d_ws, size_t ws_size,
                              hipStream_t stream)
{
  const void* gemb=d_in[0];
  const void* pemb=d_in[1];
  const void* symf=d_in[2];
  const void* ppi =d_in[3];
  const void* symW=d_in[4];
  const void* symb=d_in[5];
  const void* slng=d_in[6];   // ones -> dtype probe
  const void* slnb=d_in[7];
  const void* tte =d_in[8];
  const void* Wqkv=d_in[9];
  const void* bqkv=d_in[10];
  const void* bo  =d_in[12];
  const void* Wo  =d_in[11];
  const void* ln1g=d_in[13];
  const void* ln1b=d_in[14];
  const void* ln2g=d_in[15];
  const void* ln2b=d_in[16];
  const void* W1  =d_in[17];
  const void* b1  =d_in[18];
  const void* W2  =d_in[19];
  const void* b2  =d_in[20];
  const void* flng=d_in[21];
  const void* flnb=d_in[22];
  const void* olng=d_in[23];
  const void* olnb=d_in[24];

  u16* xbuf  =(u16*)d_ws;                 // 32768*4*256 = 33,554,432 elts (bf16)
  u16* wf_sym=xbuf + 33554432;            // 16384
  u16* wf_qkv=wf_sym + 16384;             // 3*196608
  u16* wf_o  =wf_qkv + 589824;            // 3*65536
  u16* wf_1  =wf_o  + 196608;
  u16* wf_2  =wf_1  + 196608;

  repack_kernel<<<2336,64,0,stream>>>(symW,Wqkv,Wo,W1,W2, wf_sym,wf_qkv,wf_o,wf_1,wf_2, slng);
  prep_kernel<<<512,256,0,stream>>>(gemb,pemb,symf,ppi,wf_sym,symb,slng,slnb,tte,xbuf);
  for (int lay=0; lay<3; lay++){
    attn_kernel<<<4096,256,0,stream>>>(xbuf,wf_qkv,bqkv,wf_o,bo,ln1g,ln1b,slng,lay);
    ffn_kernel<<<2048,256,0,stream>>>(xbuf,wf_1,b1,wf_2,b2,ln2g,ln2b,slng,lay);
  }
  final_kernel<<<2048,256,0,stream>>>(xbuf,flng,flnb,olng,olnb,d_out);
}